// Round 1
// baseline (351.629 us; speedup 1.0000x reference)
//
#include <hip/hip_runtime.h>

// SSIM_13443247637111 — fused separable-Gaussian SSIM + masked global reduction.
// B=16, CH=3, H=W=512, window 11x11 sigma 1.5, zero padding 5.

#define BATCH 16
#define CHANS 3
#define IMH 512
#define IMW 512
#define WSZ 11
#define PADW 5
#define TSX 32              // output tile width
#define TSY 32              // output tile height
#define HALO (TSX + WSZ - 1)  // 42
#define LDS_STRIDE 44       // padded row stride for raw tiles

__global__ __launch_bounds__(256) void ssim_main(
    const float* __restrict__ img1, const float* __restrict__ img2,
    const float* __restrict__ match, double* __restrict__ acc)
{
    __shared__ float s1[HALO][LDS_STRIDE];
    __shared__ float s2[HALO][LDS_STRIDE];
    __shared__ float sm[HALO][LDS_STRIDE];
    __shared__ float hf[6][HALO][TSX];   // horizontal-pass intermediates
    __shared__ float redn[4], redd[4];

    const int tx = threadIdx.x;            // 0..31
    const int ty = threadIdx.y;            // 0..7
    const int tid = ty * 32 + tx;
    const int bc = blockIdx.z;             // 0..47
    const int b = bc / CHANS;
    const int c = bc % CHANS;
    const int ox = blockIdx.x * TSX;
    const int oy = blockIdx.y * TSY;

    const float* p1 = img1 + (size_t)(b * CHANS + c) * IMH * IMW;
    const float* p2 = img2 + (size_t)(b * CHANS + c) * IMH * IMW;
    const float* pm = match + (size_t)b * IMH * IMW;

    // ---- load 42x42 halo tiles (zero-padded at image borders) ----
    for (int idx = tid; idx < HALO * HALO; idx += 256) {
        int r = idx / HALO;
        int col = idx - r * HALO;
        int gy = oy - PADW + r;
        int gx = ox - PADW + col;
        bool ok = (gx >= 0) & (gx < IMW) & (gy >= 0) & (gy < IMH);
        int off = gy * IMW + gx;
        s1[r][col] = ok ? p1[off] : 0.0f;
        s2[r][col] = ok ? p2[off] : 0.0f;
        sm[r][col] = ok ? pm[off] : 0.0f;
    }

    // ---- normalized gaussian weights (per-thread registers) ----
    float g[WSZ];
    {
        float s = 0.0f;
        #pragma unroll
        for (int i = 0; i < WSZ; ++i) {
            float d = (float)(i - PADW);
            g[i] = expf(-(d * d) / 4.5f);   // 2*sigma^2 = 4.5
            s += g[i];
        }
        #pragma unroll
        for (int i = 0; i < WSZ; ++i) g[i] /= s;
    }

    __syncthreads();

    // ---- horizontal separable pass: 42 rows x 32 cols, 6 fields ----
    for (int r = ty; r < HALO; r += 8) {
        float a1 = 0.f, a2 = 0.f, a3 = 0.f, a4 = 0.f, a5 = 0.f, am = 0.f;
        #pragma unroll
        for (int k = 0; k < WSZ; ++k) {
            float x1 = s1[r][tx + k];
            float x2 = s2[r][tx + k];
            float w = g[k];
            a1 += w * x1;
            a2 += w * x2;
            a3 += w * x1 * x1;
            a4 += w * x2 * x2;
            a5 += w * x1 * x2;
            am += sm[r][tx + k];            // box: unweighted sum, scale later
        }
        hf[0][r][tx] = a1;
        hf[1][r][tx] = a2;
        hf[2][r][tx] = a3;
        hf[3][r][tx] = a4;
        hf[4][r][tx] = a5;
        hf[5][r][tx] = am;
    }
    __syncthreads();

    // ---- vertical pass + SSIM + masked accumulation ----
    const float C1 = 1e-4f;   // 0.01^2
    const float C2 = 9e-4f;   // 0.03^2
    float num = 0.0f, den = 0.0f;

    for (int r = ty; r < TSY; r += 8) {
        float mu1 = 0.f, mu2 = 0.f, x11 = 0.f, x22 = 0.f, x12 = 0.f, mb = 0.f;
        #pragma unroll
        for (int k = 0; k < WSZ; ++k) {
            float w = g[k];
            mu1 += w * hf[0][r + k][tx];
            mu2 += w * hf[1][r + k][tx];
            x11 += w * hf[2][r + k][tx];
            x22 += w * hf[3][r + k][tx];
            x12 += w * hf[4][r + k][tx];
            mb  += hf[5][r + k][tx];
        }
        float mu1s = mu1 * mu1;
        float mu2s = mu2 * mu2;
        float mu12 = mu1 * mu2;
        float sg1 = x11 - mu1s;
        float sg2 = x22 - mu2s;
        float sg12 = x12 - mu12;
        float ssim = ((2.0f * mu12 + C1) * (2.0f * sg12 + C2)) /
                     ((mu1s + mu2s + C1) * (sg1 + sg2 + C2));
        float m = mb * (1.0f / 121.0f) + 1e-7f;
        float mask = (m > 0.5f) ? (1.0f + 1e-7f) : 1e-7f;
        num += (1.0f - ssim) * mask;
        den += mask;
    }

    // ---- block reduction: wave shuffle (width 64) then cross-wave LDS ----
    for (int off = 32; off > 0; off >>= 1) {
        num += __shfl_down(num, off);
        den += __shfl_down(den, off);
    }
    int wave = tid >> 6;
    int lane = tid & 63;
    if (lane == 0) { redn[wave] = num; redd[wave] = den; }
    __syncthreads();
    if (tid == 0) {
        float n = redn[0] + redn[1] + redn[2] + redn[3];
        atomicAdd(&acc[0], (double)n);
        if (c == 0) {
            float d = redd[0] + redd[1] + redd[2] + redd[3];
            atomicAdd(&acc[1], (double)d);
        }
    }
}

__global__ void init_acc(double* acc) {
    acc[0] = 0.0;
    acc[1] = 0.0;
}

__global__ void finalize(const double* __restrict__ acc, float* __restrict__ out) {
    out[0] = (float)(acc[0] / acc[1] / 3.0);
}

extern "C" void kernel_launch(void* const* d_in, const int* in_sizes, int n_in,
                              void* d_out, int out_size, void* d_ws, size_t ws_size,
                              hipStream_t stream) {
    const float* img1  = (const float*)d_in[0];
    const float* img2  = (const float*)d_in[1];
    const float* match = (const float*)d_in[2];
    float* out = (float*)d_out;
    double* acc = (double*)d_ws;   // acc[0]=numerator sum, acc[1]=mask sum

    init_acc<<<1, 1, 0, stream>>>(acc);

    dim3 grid(IMW / TSX, IMH / TSY, BATCH * CHANS);   // 16 x 16 x 48
    dim3 block(32, 8, 1);
    ssim_main<<<grid, block, 0, stream>>>(img1, img2, match, acc);

    finalize<<<1, 1, 0, stream>>>(acc, out);
}

// Round 2
// 245.534 us; speedup vs baseline: 1.4321x; 1.4321x over previous
//
#include <hip/hip_runtime.h>

// SSIM_13443247637111 — fused separable SSIM, V-first ring-buffer design.
// B=16, CH=3, 512x512, 11x11 gaussian sigma 1.5, zero padding 5.
//
// Round-2 structure (LDS-throughput bound fix):
//  - all LDS traffic is float4 (ds_read_b128 / ds_write_b128)
//  - vertical pass FIRST (3 raw fields x 11 taps), horizontal second
//    (6 derived fields x 11 taps) -> 11-tap-heavy direction reads 3 arrays
//  - rolling 18-row raw ring buffer + 8-row derived-field buffer:
//    LDS = 3*18*84*4 + 6*8*84*4 = 34.3 KB -> 4 blocks/CU capacity
//  - block = 256 thr, strip = 64 wide x 256 tall, grid 8x2x48 = 768 blocks
//    (= exactly 3 blocks/CU, no tail)

#define BATCH 16
#define CHANS 3
#define IMH 512
#define IMW 512
#define STRIPW 64
#define STRIPH 256
#define RINGR 18            // raw rows resident: y-5 .. y+12 for an 8-row super
#define LDSW 84             // padded row width; col c <-> x = bx*64 + c - 8
#define SUP 8               // output rows per super-iteration
#define NSUP (STRIPH / SUP) // 32
#define NQ 20               // float4 quads per staged row (80 cols)

__device__ __forceinline__ float4 ld4s(const float* p) { return *(const float4*)p; }
__device__ __forceinline__ void st4s(float* p, float4 v) { *(float4*)p = v; }
__device__ __forceinline__ void fma4(float4& a, float w, float4 x) {
    a.x = fmaf(w, x.x, a.x); a.y = fmaf(w, x.y, a.y);
    a.z = fmaf(w, x.z, a.z); a.w = fmaf(w, x.w, a.w);
}
__device__ __forceinline__ void fma4m(float4& a, float w, float4 x, float4 y) {
    a.x = fmaf(w, x.x * y.x, a.x); a.y = fmaf(w, x.y * y.y, a.y);
    a.z = fmaf(w, x.z * y.z, a.z); a.w = fmaf(w, x.w * y.w, a.w);
}
__device__ __forceinline__ void add4(float4& a, float4 x) {
    a.x += x.x; a.y += x.y; a.z += x.z; a.w += x.w;
}

// gaussian-weighted horizontal 11-tap conv: 4 outputs from 20-float window
__device__ __forceinline__ void convg(const float* __restrict__ row, int cb,
                                      const float* __restrict__ g, float out[4]) {
    float w[20];
    #pragma unroll
    for (int i = 0; i < 5; ++i) {
        float4 v = ld4s(row + cb + 4 * i);
        w[4*i+0] = v.x; w[4*i+1] = v.y; w[4*i+2] = v.z; w[4*i+3] = v.w;
    }
    #pragma unroll
    for (int j = 0; j < 4; ++j) {
        float a = 0.0f;
        #pragma unroll
        for (int k = 0; k < 11; ++k) a = fmaf(g[k], w[3 + j + k], a);
        out[j] = a;
    }
}

// unweighted (box) horizontal 11-tap sum
__device__ __forceinline__ void convb(const float* __restrict__ row, int cb,
                                      float out[4]) {
    float w[20];
    #pragma unroll
    for (int i = 0; i < 5; ++i) {
        float4 v = ld4s(row + cb + 4 * i);
        w[4*i+0] = v.x; w[4*i+1] = v.y; w[4*i+2] = v.z; w[4*i+3] = v.w;
    }
    #pragma unroll
    for (int j = 0; j < 4; ++j) {
        float a = 0.0f;
        #pragma unroll
        for (int k = 0; k < 11; ++k) a += w[3 + j + k];
        out[j] = a;
    }
}

__global__ __launch_bounds__(256) void ssim_main(
    const float* __restrict__ img1, const float* __restrict__ img2,
    const float* __restrict__ match, double* __restrict__ acc)
{
    __shared__ __align__(16) float ring1[RINGR][LDSW];
    __shared__ __align__(16) float ring2[RINGR][LDSW];
    __shared__ __align__(16) float ringm[RINGR][LDSW];
    __shared__ __align__(16) float fld[6][SUP][LDSW];
    __shared__ float redn[4], redd[4];

    const int tid = threadIdx.x;
    const int bc = blockIdx.z;
    const int b = bc / CHANS;
    const int c = bc - b * CHANS;
    const int ystart = blockIdx.y * STRIPH;
    const int bx0 = blockIdx.x * STRIPW - 8;   // global x of LDS col 0

    const float* p1 = img1 + (size_t)(b * CHANS + c) * (IMH * IMW);
    const float* p2 = img2 + (size_t)(b * CHANS + c) * (IMH * IMW);
    const float* pm = match + (size_t)b * (IMH * IMW);

    // normalized gaussian weights (expf matches reference to fp noise)
    float g[11];
    {
        float s = 0.0f;
        #pragma unroll
        for (int i = 0; i < 11; ++i) {
            float d = (float)(i - 5);
            g[i] = expf(-(d * d) / 4.5f);
            s += g[i];
        }
        #pragma unroll
        for (int i = 0; i < 11; ++i) g[i] /= s;
    }

    float num = 0.0f, den = 0.0f;

    auto stage = [&](int gy0, int nrows) {
        for (int t = tid; t < nrows * NQ; t += 256) {
            int r = t / NQ, q = t - r * NQ;
            int gy = gy0 + r;
            int slot = (gy + 36) % RINGR;
            int gx = bx0 + 4 * q;
            float4 v1, v2, vm;
            if ((unsigned)gy < IMH && (unsigned)gx <= (IMW - 4)) {
                const float* base = p1 + gy * IMW + gx;
                v1 = ld4s(base);
                v2 = ld4s(p2 + gy * IMW + gx);
                vm = ld4s(pm + gy * IMW + gx);
            } else if ((unsigned)gy < IMH) {
                float t1[4], t2[4], tm[4];
                #pragma unroll
                for (int e = 0; e < 4; ++e) {
                    int x = gx + e;
                    bool ok = (unsigned)x < IMW;
                    int off = gy * IMW + (ok ? x : 0);
                    t1[e] = ok ? p1[off] : 0.0f;
                    t2[e] = ok ? p2[off] : 0.0f;
                    tm[e] = ok ? pm[off] : 0.0f;
                }
                v1 = make_float4(t1[0], t1[1], t1[2], t1[3]);
                v2 = make_float4(t2[0], t2[1], t2[2], t2[3]);
                vm = make_float4(tm[0], tm[1], tm[2], tm[3]);
            } else {
                v1 = v2 = vm = make_float4(0.f, 0.f, 0.f, 0.f);
            }
            st4s(&ring1[slot][4 * q], v1);
            st4s(&ring2[slot][4 * q], v2);
            st4s(&ringm[slot][4 * q], vm);
        }
    };

    // prologue: raw rows ystart-5 .. ystart+4
    stage(ystart - 5, 10);

    for (int s = 0; s < NSUP; ++s) {
        const int ybase = ystart + s * SUP;

        // stage the 8 new raw rows this super needs (ybase+5 .. ybase+12).
        // safe: slots being overwritten were last read by V of super s-1,
        // which completed before the barrier after that V phase.
        stage(ybase + 5, SUP);
        __syncthreads();   // B1: staging visible; fld free (H of s-1 done)

        // ---- vertical pass: 8 rows x 20 quads (80 cols incl. halo) ----
        if (tid < SUP * NQ) {
            int r = tid / NQ, q = tid - r * NQ;
            int cq = 4 * q;
            int y = ybase + r;
            int sr = (y - 5 + 36) % RINGR;
            float4 a1 = make_float4(0,0,0,0), a2 = a1, a3 = a1,
                   a4 = a1, a5 = a1, am = a1;
            #pragma unroll
            for (int k = 0; k < 11; ++k) {
                float4 x1 = ld4s(&ring1[sr][cq]);
                float4 x2 = ld4s(&ring2[sr][cq]);
                float4 xm = ld4s(&ringm[sr][cq]);
                float w = g[k];
                fma4(a1, w, x1);
                fma4(a2, w, x2);
                fma4m(a3, w, x1, x1);
                fma4m(a4, w, x2, x2);
                fma4m(a5, w, x1, x2);
                add4(am, xm);
                sr++; if (sr >= RINGR) sr -= RINGR;
            }
            st4s(&fld[0][r][cq], a1);
            st4s(&fld[1][r][cq], a2);
            st4s(&fld[2][r][cq], a3);
            st4s(&fld[3][r][cq], a4);
            st4s(&fld[4][r][cq], a5);
            st4s(&fld[5][r][cq], am);
        }
        __syncthreads();   // B2: fld visible; ring free for next stage

        // ---- horizontal pass + SSIM: 8 rows x 16 quads (64 cols) ----
        if (tid < SUP * 16) {
            int r = tid >> 4, q = tid & 15;
            int cb = 4 * q;   // window w[0] = col 4q; outputs at cols 4q+8..11
            float mu1[4], mu2[4], m11[4], m22[4], m12[4], mb[4];
            convg(fld[0][r], cb, g, mu1);
            convg(fld[1][r], cb, g, mu2);
            convg(fld[2][r], cb, g, m11);
            convg(fld[3][r], cb, g, m22);
            convg(fld[4][r], cb, g, m12);
            convb(fld[5][r], cb, mb);
            #pragma unroll
            for (int j = 0; j < 4; ++j) {
                float mu1s = mu1[j] * mu1[j];
                float mu2s = mu2[j] * mu2[j];
                float mu12 = mu1[j] * mu2[j];
                float sg1  = m11[j] - mu1s;
                float sg2  = m22[j] - mu2s;
                float sg12 = m12[j] - mu12;
                float ssim = ((2.0f * mu12 + 1e-4f) * (2.0f * sg12 + 9e-4f)) /
                             ((mu1s + mu2s + 1e-4f) * (sg1 + sg2 + 9e-4f));
                float m = mb[j] * (1.0f / 121.0f) + 1e-7f;
                float mask = (m > 0.5f) ? (1.0f + 1e-7f) : 1e-7f;
                num += (1.0f - ssim) * mask;
                den += mask;
            }
        }
    }

    // ---- block reduction: wave shuffle (width 64) then cross-wave LDS ----
    for (int off = 32; off > 0; off >>= 1) {
        num += __shfl_down(num, off);
        den += __shfl_down(den, off);
    }
    int wave = tid >> 6;
    int lane = tid & 63;
    if (lane == 0) { redn[wave] = num; redd[wave] = den; }
    __syncthreads();
    if (tid == 0) {
        float n = redn[0] + redn[1] + redn[2] + redn[3];
        atomicAdd(&acc[0], (double)n);
        if (c == 0) {
            float d = redd[0] + redd[1] + redd[2] + redd[3];
            atomicAdd(&acc[1], (double)d);
        }
    }
}

__global__ void init_acc(double* acc) {
    acc[0] = 0.0;
    acc[1] = 0.0;
}

__global__ void finalize(const double* __restrict__ acc, float* __restrict__ out) {
    out[0] = (float)(acc[0] / acc[1] / 3.0);
}

extern "C" void kernel_launch(void* const* d_in, const int* in_sizes, int n_in,
                              void* d_out, int out_size, void* d_ws, size_t ws_size,
                              hipStream_t stream) {
    const float* img1  = (const float*)d_in[0];
    const float* img2  = (const float*)d_in[1];
    const float* match = (const float*)d_in[2];
    float* out = (float*)d_out;
    double* acc = (double*)d_ws;

    init_acc<<<1, 1, 0, stream>>>(acc);

    dim3 grid(IMW / STRIPW, IMH / STRIPH, BATCH * CHANS);  // 8 x 2 x 48 = 768
    dim3 block(256, 1, 1);
    ssim_main<<<grid, block, 0, stream>>>(img1, img2, match, acc);

    finalize<<<1, 1, 0, stream>>>(acc, out);
}